// Round 2
// baseline (140.891 us; speedup 1.0000x reference)
//
#include <hip/hip_runtime.h>
#include <hip/hip_bf16.h>

#define N_TOK 8192
#define DIM   512
#define FDIM  128
#define BM    32

typedef __attribute__((ext_vector_type(8))) short short8;
typedef __attribute__((ext_vector_type(4))) float floatx4;

__device__ inline short f2bf(float f) {
    union { float f; unsigned u; } v; v.f = f;
    unsigned r = (v.u + 0x7FFF + ((v.u >> 16) & 1)) >> 16;  // RNE, inputs are finite
    return (short)r;
}

// Blocks [0,256): fp32 routing, 32 tokens/block, 8 threads/token, dims
// interleaved for 128B-contiguous loads; 3-stage xor-shuffle reduce.
// Blocks [256,1024): repack w1a/w1b/w2 into bf16 MFMA B-fragment order:
// frag f -> 512 shorts at pw[f*512 + lane*8 + j].
__global__ __launch_bounds__(256) void k_prep(
    const float* __restrict__ x,
    const float* __restrict__ wn0, const float* __restrict__ bn0,
    const float* __restrict__ wn1, const float* __restrict__ bn1,
    const float* __restrict__ wn2, const float* __restrict__ bn2,
    const float* __restrict__ w1a, const float* __restrict__ w1b,
    const float* __restrict__ w2,
    int* __restrict__ counts, int* __restrict__ lists,
    short* __restrict__ pw1a, short* __restrict__ pw1b, short* __restrict__ pw2)
{
    const int blk = blockIdx.x;
    if (blk < 256) {
        __shared__ int leafs[32];
        const int t = threadIdx.x;
        const int row = t >> 3, tpr = t & 7;       // token-row, thread-in-row
        const int tok = blk * 32 + row;
        // thread's dims: d = u*32 + tpr*4 + j, u<16, j<4
        const float* xr  = x + tok * DIM + tpr * 4;
        const float* w0p = wn0 + tpr * 4;
        const float* w1p = wn1 + tpr * 8;
        const float* w2p = wn2 + tpr * 16;
        float acc[7] = {0.f, 0.f, 0.f, 0.f, 0.f, 0.f, 0.f};
        #pragma unroll
        for (int u = 0; u < 16; ++u) {
            const float4 xv = *(const float4*)(xr + u * 32);
            const float4 w0 = *(const float4*)(w0p + u * 32);
            const float4 wa = *(const float4*)(w1p + u * 64);
            const float4 wb = *(const float4*)(w1p + u * 64 + 4);
            const float4 wc = *(const float4*)(w2p + u * 128);
            const float4 wd = *(const float4*)(w2p + u * 128 + 4);
            const float4 we = *(const float4*)(w2p + u * 128 + 8);
            const float4 wf = *(const float4*)(w2p + u * 128 + 12);
            const float xs4[4] = {xv.x, xv.y, xv.z, xv.w};
            const float w0s[4] = {w0.x, w0.y, w0.z, w0.w};
            const float w1s[8] = {wa.x, wa.y, wa.z, wa.w, wb.x, wb.y, wb.z, wb.w};
            const float w2s[16] = {wc.x, wc.y, wc.z, wc.w, wd.x, wd.y, wd.z, wd.w,
                                   we.x, we.y, we.z, we.w, wf.x, wf.y, wf.z, wf.w};
            #pragma unroll
            for (int j = 0; j < 4; ++j) {
                acc[0] += xs4[j] * w0s[j];
                acc[1] += xs4[j] * w1s[j * 2];
                acc[2] += xs4[j] * w1s[j * 2 + 1];
                acc[3] += xs4[j] * w2s[j * 4];
                acc[4] += xs4[j] * w2s[j * 4 + 1];
                acc[5] += xs4[j] * w2s[j * 4 + 2];
                acc[6] += xs4[j] * w2s[j * 4 + 3];
            }
        }
        #pragma unroll
        for (int k = 0; k < 7; ++k) {
            acc[k] += __shfl_xor(acc[k], 1, 64);
            acc[k] += __shfl_xor(acc[k], 2, 64);
            acc[k] += __shfl_xor(acc[k], 4, 64);
        }
        // rint(sigmoid(t))=1 iff t>0; branch bit = 1 - that (t==0 -> bit 1).
        int p = (acc[0] + bn0[0] > 0.f) ? 0 : 1;
        const float t1 = acc[1 + p] + bn1[p];
        p = p * 2 + ((t1 > 0.f) ? 0 : 1);
        const float t2 = acc[3 + p] + bn2[p];
        p = p * 2 + ((t2 > 0.f) ? 0 : 1);
        if (tpr == 0) leafs[row] = p;
        __syncthreads();
        if (t < 8) {
            const int l = t;
            int c = 0;
            for (int i = 0; i < 32; ++i) c += (leafs[i] == l);
            if (c > 0) {
                int base = atomicAdd(counts + l * 16, c);
                int j = 0;
                for (int i = 0; i < 32; ++i)
                    if (leafs[i] == l) lists[l * N_TOK + base + (j++)] = blk * 32 + i;
            }
        }
    } else {
        const int wid  = (blk - 256) * 4 + (threadIdx.x >> 6);
        const int lane = threadIdx.x & 63;
        const int q = lane >> 4, m = lane & 15;
        if (wid < 2048) {
            const float* src = (wid < 1024) ? w1a : w1b;
            short*       dst = (wid < 1024) ? pw1a : pw1b;
            const int f = wid & 1023;                       // (l*16+kb)*8+nt
            const int l = f >> 7, kb = (f >> 3) & 15, nt = f & 7;
            const float* s = src + l * 65536 + (kb * 32 + q * 8) * FDIM + nt * 16 + m;
            short8 o;
            #pragma unroll
            for (int j = 0; j < 8; ++j) o[j] = f2bf(s[j * FDIM]);
            *(short8*)(dst + f * 512 + lane * 8) = o;
        } else {
            const int f = wid - 2048;                       // (l*4+kb)*32+nt
            const int l = f >> 7, kb = (f >> 5) & 3, nt = f & 31;
            const float* s = w2 + l * 65536 + (kb * 32 + q * 8) * DIM + nt * 16 + m;
            short8 o;
            #pragma unroll
            for (int j = 0; j < 8; ++j) o[j] = f2bf(s[j * DIM]);
            *(short8*)(pw2 + f * 512 + lane * 8) = o;
        }
    }
}

// One block = 32 gathered tokens of one leaf, 8 waves: waves 0-3 rows 0-15,
// waves 4-7 rows 16-31 (sharing B fragments -> L1 hits). Phase1:
// h=(x@w1a+b1a)*(x@w1b+b1b) via 16x16x32 bf16 MFMA; phase2: y=h@w2+b2.
__global__ __launch_bounds__(512) void k_ffn(
    const float* __restrict__ x,
    const float* __restrict__ b1a, const float* __restrict__ b1b,
    const float* __restrict__ b2,
    const short* __restrict__ pw1a, const short* __restrict__ pw1b,
    const short* __restrict__ pw2,
    const int* __restrict__ counts, const int* __restrict__ lists,
    float* __restrict__ out)
{
    const int leaf = blockIdx.y;
    const int tile = blockIdx.x;
    const int cnt  = counts[leaf * 16];
    if (tile * BM >= cnt) return;

    __shared__ int   toks[BM];
    __shared__ short xs[BM][DIM + 8];    // +8 pad: row stride 1040B
    __shared__ short hs[BM][FDIM + 8];

    const int t = threadIdx.x;
    if (t < BM) {
        const int idx = tile * BM + t;
        toks[t] = lists[leaf * N_TOK + ((idx < cnt) ? idx : cnt - 1)];  // clamp: dup, not stored
    }
    __syncthreads();

    {   // stage x rows -> LDS bf16; thread t: row t>>4 (0..31), 32 cols
        const int row = t >> 4, c0 = (t & 15) * 32;
        const float4* src = (const float4*)(x + toks[row] * DIM + c0);
        #pragma unroll
        for (int u = 0; u < 4; ++u) {
            const float4 fa = src[u * 2], fb = src[u * 2 + 1];
            short8 o;
            o[0] = f2bf(fa.x); o[1] = f2bf(fa.y); o[2] = f2bf(fa.z); o[3] = f2bf(fa.w);
            o[4] = f2bf(fb.x); o[5] = f2bf(fb.y); o[6] = f2bf(fb.z); o[7] = f2bf(fb.w);
            *(short8*)&xs[row][c0 + u * 8] = o;
        }
    }
    __syncthreads();

    const int wave = t >> 6, lane = t & 63;
    const int mh = (wave >> 2) * 16;     // row-half base
    const int wq = wave & 3;
    const int qd = lane >> 4, mm = lane & 15;

    // ---- phase 1: M=16 (rows mh..mh+15), N=128 (n-tiles wq*2, wq*2+1), K=512
    floatx4 accA0 = {0,0,0,0}, accA1 = {0,0,0,0}, accB0 = {0,0,0,0}, accB1 = {0,0,0,0};
    const int nt0 = wq * 2, nt1 = wq * 2 + 1;
    #pragma unroll
    for (int kb = 0; kb < 16; ++kb) {
        const short8 af  = *(const short8*)&xs[mh + mm][kb * 32 + qd * 8];
        const short8 ba0 = *(const short8*)(pw1a + (((leaf * 16 + kb) * 8 + nt0) * 512) + lane * 8);
        const short8 ba1 = *(const short8*)(pw1a + (((leaf * 16 + kb) * 8 + nt1) * 512) + lane * 8);
        const short8 bb0 = *(const short8*)(pw1b + (((leaf * 16 + kb) * 8 + nt0) * 512) + lane * 8);
        const short8 bb1 = *(const short8*)(pw1b + (((leaf * 16 + kb) * 8 + nt1) * 512) + lane * 8);
        accA0 = __builtin_amdgcn_mfma_f32_16x16x32_bf16(af, ba0, accA0, 0, 0, 0);
        accA1 = __builtin_amdgcn_mfma_f32_16x16x32_bf16(af, ba1, accA1, 0, 0, 0);
        accB0 = __builtin_amdgcn_mfma_f32_16x16x32_bf16(af, bb0, accB0, 0, 0, 0);
        accB1 = __builtin_amdgcn_mfma_f32_16x16x32_bf16(af, bb1, accB1, 0, 0, 0);
    }
    {   // gated bias epilogue -> hs (bf16), C/D layout: col=lane&15, row=qd*4+r
        const int c0 = nt0 * 16 + mm, c1 = nt1 * 16 + mm;
        const float ba0 = b1a[leaf * FDIM + c0], ba1 = b1a[leaf * FDIM + c1];
        const float bb0 = b1b[leaf * FDIM + c0], bb1 = b1b[leaf * FDIM + c1];
        #pragma unroll
        for (int r = 0; r < 4; ++r) {
            const int row = mh + qd * 4 + r;
            hs[row][c0] = f2bf((accA0[r] + ba0) * (accB0[r] + bb0));
            hs[row][c1] = f2bf((accA1[r] + ba1) * (accB1[r] + bb1));
        }
    }
    __syncthreads();

    // ---- phase 2: M=16, N=512 (n-tiles wq*8..wq*8+7), K=128
    floatx4 acc[8];
    #pragma unroll
    for (int j = 0; j < 8; ++j) acc[j] = (floatx4){0, 0, 0, 0};
    #pragma unroll
    for (int kb = 0; kb < 4; ++kb) {
        const short8 af = *(const short8*)&hs[mh + mm][kb * 32 + qd * 8];
        #pragma unroll
        for (int j = 0; j < 8; ++j) {
            const int nt = wq * 8 + j;
            const short8 bf = *(const short8*)(pw2 + (((leaf * 4 + kb) * 32 + nt) * 512) + lane * 8);
            acc[j] = __builtin_amdgcn_mfma_f32_16x16x32_bf16(af, bf, acc[j], 0, 0, 0);
        }
    }
    const int rem = cnt - tile * BM;
    #pragma unroll
    for (int j = 0; j < 8; ++j) {
        const int col = (wq * 8 + j) * 16 + mm;
        const float bias = b2[leaf * DIM + col];
        #pragma unroll
        for (int r = 0; r < 4; ++r) {
            const int row = mh + qd * 4 + r;
            if (row < rem) out[toks[row] * DIM + col] = acc[j][r] + bias;
        }
    }
}

extern "C" void kernel_launch(void* const* d_in, const int* in_sizes, int n_in,
                              void* d_out, int out_size, void* d_ws, size_t ws_size,
                              hipStream_t stream) {
    const float* x   = (const float*)d_in[0];
    // d_in[1] = training (forward value identical either way; ignored)
    const float* wn0 = (const float*)d_in[2];
    const float* bn0 = (const float*)d_in[3];
    const float* wn1 = (const float*)d_in[4];
    const float* bn1 = (const float*)d_in[5];
    const float* wn2 = (const float*)d_in[6];
    const float* bn2 = (const float*)d_in[7];
    const float* w1a = (const float*)d_in[8];
    const float* b1a = (const float*)d_in[9];
    const float* w1b = (const float*)d_in[10];
    const float* b1b = (const float*)d_in[11];
    const float* w2  = (const float*)d_in[12];
    const float* b2  = (const float*)d_in[13];
    float* out = (float*)d_out;

    char* ws = (char*)d_ws;
    int*   counts = (int*)(ws);                               // 8 counters, stride 16 ints
    int*   lists  = (int*)(ws + 512);                         // 8 x 8192 ints
    short* pw1a   = (short*)(ws + 262656);                    // 1024 frags x 512 bf16
    short* pw1b   = (short*)(ws + 262656 + 1048576);
    short* pw2    = (short*)(ws + 262656 + 2097152);

    hipMemsetAsync(counts, 0, 512, stream);
    k_prep<<<1024, 256, 0, stream>>>(x, wn0, bn0, wn1, bn1, wn2, bn2,
                                     w1a, w1b, w2, counts, lists, pw1a, pw1b, pw2);
    k_ffn<<<dim3(256, 8), 512, 0, stream>>>(x, b1a, b1b, b2, pw1a, pw1b, pw2,
                                            counts, lists, out);
}